// Round 4
// baseline (357.170 us; speedup 1.0000x reference)
//
#include <hip/hip_runtime.h>
#include <hip/hip_bf16.h>
#include <cstdint>

#define NHEAD 8
#define HD 32
#define DM 256
#define HH 56
#define WWID 56
#define HW 3136          // 56*56
#define NB 2
#define SCALE 0.17677669529663687f   // 32^-0.5

typedef unsigned int u32;
typedef __attribute__((ext_vector_type(8))) short short8;   // 8 bf16 = 4 VGPRs
typedef __attribute__((ext_vector_type(4))) float floatx4;

#define BF2F_LO(u) __uint_as_float((u) << 16)
#define BF2F_HI(u) __uint_as_float((u) & 0xffff0000u)

// ---------------------------------------------------------------------------
// Convert all four weight matrices fp32 -> bf16. wq,wk,wv stacked into
// wcat[768][256]; wo into wob[256][256].
// ---------------------------------------------------------------------------
__global__ __launch_bounds__(256) void convert_w(
    const float* __restrict__ wq, const float* __restrict__ wk,
    const float* __restrict__ wv, const float* __restrict__ wo,
    __hip_bfloat16* __restrict__ wcat, __hip_bfloat16* __restrict__ wob)
{
    const int gid = blockIdx.x * 256 + threadIdx.x;
    const int idx4 = gid << 2;                 // 0 .. 262140
    const int sel = idx4 >> 16;                // 0..3
    const int off = idx4 & 65535;
    const float* src = sel == 0 ? wq : (sel == 1 ? wk : (sel == 2 ? wv : wo));
    __hip_bfloat16* dst = sel < 3 ? (wcat + (sel << 16) + off) : (wob + off);
    float4 f = *(const float4*)&src[off];
    union { ushort4 u; __hip_bfloat16 s[4]; } pk;
    pk.s[0] = __float2bfloat16(f.x); pk.s[1] = __float2bfloat16(f.y);
    pk.s[2] = __float2bfloat16(f.z); pk.s[3] = __float2bfloat16(f.w);
    *(ushort4*)dst = pk.u;
}

// ---------------------------------------------------------------------------
// Transpose-convert x [b][c][p] fp32 -> xT [b][p][c] bf16 (c contiguous).
// ---------------------------------------------------------------------------
__global__ __launch_bounds__(256) void transpose_x(
    const float* __restrict__ x, __hip_bfloat16* __restrict__ xT)
{
    __shared__ float tile[32][33];
    const int b = blockIdx.z, p0 = blockIdx.x * 32, c0 = blockIdx.y * 32;
    const int tx = threadIdx.x & 31, ty = threadIdx.x >> 5;   // ty in [0,8)
    const float* xb = x + (size_t)b * DM * HW;
    #pragma unroll
    for (int i = 0; i < 4; ++i)
        tile[ty + i * 8][tx] = xb[(size_t)(c0 + ty + i * 8) * HW + p0 + tx];
    __syncthreads();
    __hip_bfloat16* xo = xT + (size_t)b * HW * DM;
    #pragma unroll
    for (int i = 0; i < 4; ++i)
        xo[(size_t)(p0 + ty + i * 8) * DM + c0 + tx] =
            __float2bfloat16(tile[tx][ty + i * 8]);
}

// ---------------------------------------------------------------------------
// MFMA GEMM: A bf16 [M][256] k-contig; B as Bm[b][n][k] k-contig.
// BM=128, BN=64, BK=32, 4 waves, wave = 64x32 via 4x2 tiles of 16x16x32.
// MODE 0: M=768 fused qkv -> q/k/v bf16 [b][h][p][d].
// MODE 1: M=256 out-proj  -> fp32 d_out [b][c][p].
// ---------------------------------------------------------------------------
template<int MODE>
__global__ __launch_bounds__(256) void gemm_mfma(
    const __hip_bfloat16* __restrict__ A,
    const __hip_bfloat16* __restrict__ Bm,
    const float* __restrict__ b0, const float* __restrict__ b1,
    const float* __restrict__ b2,
    void* __restrict__ o0, void* __restrict__ o1, void* __restrict__ o2)
{
    const int bb = blockIdx.z;
    const int n0 = blockIdx.x * 64;
    const int m0 = blockIdx.y * 128;
    const __hip_bfloat16* Bb = Bm + (size_t)bb * HW * DM + (size_t)n0 * DM;

    __shared__ __align__(16) __hip_bfloat16 As[128][40];
    __shared__ __align__(16) __hip_bfloat16 Bs[64][40];

    const int t = threadIdx.x;
    const int wave = t >> 6, lane = t & 63;
    const int quad = lane >> 4, l16 = lane & 15;
    const int mw = (wave & 1) * 64, nw = (wave >> 1) * 32;

    floatx4 acc[4][2] = {};

    const int am = t >> 2, ak = (t & 3) << 3;
    const int bn = t >> 2, bk = (t & 3) << 3;

    for (int k0g = 0; k0g < DM; k0g += 32) {
        *(uint4*)&As[am][ak]      = *(const uint4*)&A[(size_t)(m0 + am) * DM + k0g + ak];
        *(uint4*)&As[am + 64][ak] = *(const uint4*)&A[(size_t)(m0 + am + 64) * DM + k0g + ak];
        *(uint4*)&Bs[bn][bk]      = *(const uint4*)&Bb[(size_t)bn * DM + k0g + bk];
        __syncthreads();
        short8 af[4], bf[2];
        #pragma unroll
        for (int mt = 0; mt < 4; ++mt)
            af[mt] = *(const short8*)&As[mw + mt * 16 + l16][quad * 8];
        #pragma unroll
        for (int nt = 0; nt < 2; ++nt)
            bf[nt] = *(const short8*)&Bs[nw + nt * 16 + l16][quad * 8];
        #pragma unroll
        for (int mt = 0; mt < 4; ++mt)
            #pragma unroll
            for (int nt = 0; nt < 2; ++nt)
                acc[mt][nt] = __builtin_amdgcn_mfma_f32_16x16x32_bf16(
                    af[mt], bf[nt], acc[mt][nt], 0, 0, 0);
        __syncthreads();
    }

    if (MODE == 0) {
        #pragma unroll
        for (int mt = 0; mt < 4; ++mt) {
            const int gm = m0 + mw + mt * 16 + quad * 4;
            const int proj = gm >> 8;
            const int c = gm & 255;
            const int h = c >> 5, d0 = c & 31;
            const float* bptr = proj == 0 ? b0 : (proj == 1 ? b1 : b2);
            __hip_bfloat16* op = (__hip_bfloat16*)(proj == 0 ? o0 : (proj == 1 ? o1 : o2));
            const size_t base = ((size_t)(bb * NHEAD + h) * HW) * HD + d0;
            float bias[4] = {bptr[c], bptr[c + 1], bptr[c + 2], bptr[c + 3]};
            #pragma unroll
            for (int nt = 0; nt < 2; ++nt) {
                const int p = n0 + nw + nt * 16 + l16;
                union { ushort4 u; __hip_bfloat16 s[4]; } pk;
                #pragma unroll
                for (int r = 0; r < 4; ++r)
                    pk.s[r] = __float2bfloat16(acc[mt][nt][r] + bias[r]);
                *(ushort4*)&op[base + (size_t)p * HD] = pk.u;
            }
        }
    } else {
        float* yo = (float*)o0;
        #pragma unroll
        for (int mt = 0; mt < 4; ++mt) {
            const int gc = m0 + mw + mt * 16 + quad * 4;
            #pragma unroll
            for (int r = 0; r < 4; ++r) {
                const float bias = b0[gc + r];
                #pragma unroll
                for (int nt = 0; nt < 2; ++nt) {
                    const int p = n0 + nw + nt * 16 + l16;
                    yo[(size_t)(bb * DM + gc + r) * HW + p] = acc[mt][nt][r] + bias;
                }
            }
        }
    }
}

// ---------------------------------------------------------------------------
// Stage 2: sliding-window attention, LDS halo tiling, SINGLE fused loop.
// Block = 128 threads, 2 rows x 56 cols of one (b,head). Grid 28 x 8 x 2.
// Per neighbor: read K chunks -> score -> e=exp(s*scale) -> read V chunks ->
// of += wt*V (unnormalized), sum += (valid? e : 1). Normalize at end.
// No wv49[] array -> live set ~110 VGPR, no scratch spills (R3 lesson:
// VGPR=256 + 187 MB scratch traffic from keeping 49 weights live).
// Zero-pad semantics: invalid neighbor adds exp(0)=1 to denom, 0 to numer.
// ---------------------------------------------------------------------------
#define HROWS 8                    // 2 + 6 halo
#define HPOS  (HROWS * WWID)       // 448
#define HPP   (HPOS + 6)           // 454, +3 guard each side

__global__ __launch_bounds__(128) void attn_win(
    const __hip_bfloat16* __restrict__ q,
    const __hip_bfloat16* __restrict__ k,
    const __hip_bfloat16* __restrict__ v,
    __hip_bfloat16* __restrict__ out)
{
    __shared__ uint4 kh[4][HPP];   // [d_chunk][pos'], 29,056 B
    __shared__ uint4 vh[4][HPP];   // 29,056 B

    const int t = threadIdx.x;
    const int tile = blockIdx.x;          // 0..27
    const int h = blockIdx.y, b = blockIdx.z;
    const int y0 = tile * 2;
    const size_t base = (size_t)(b * NHEAD + h) * HW * HD;
    const __hip_bfloat16* kp = k + base;
    const __hip_bfloat16* vp = v + base;

    // ---- stage halo: rows y0-3 .. y0+4, zero where y OOB. 1792 16B units.
    for (int it = 0; it < 14; ++it) {
        const int u = t + (it << 7);
        const int pos = u >> 2, ch = u & 3;
        const int hr = pos / WWID;
        const int gx = pos - hr * WWID;
        const int gy = y0 - 3 + hr;
        uint4 kv = make_uint4(0, 0, 0, 0), vv = make_uint4(0, 0, 0, 0);
        if ((unsigned)gy < HH) {
            const size_t g = (size_t)(gy * WWID + gx) * HD + (ch << 3);
            kv = *(const uint4*)&kp[g];
            vv = *(const uint4*)&vp[g];
        }
        kh[ch][pos + 3] = kv;
        vh[ch][pos + 3] = vv;
    }
    // zero the 6 guard positions in all 4 chunks, both arrays
    if (t < 48) {
        const int ps = t % 6;
        const int pp = ps < 3 ? ps : HPOS + ps;
        const int ch = (t / 6) & 3;
        const uint4 z = make_uint4(0, 0, 0, 0);
        if (t < 24) kh[ch][pp] = z; else vh[ch][pp] = z;
    }
    __syncthreads();

    if (t < 112) {
        const int lx = t % WWID;
        const int p = y0 * WWID + t;

        float qf[32];
        {
            const uint4* qp = (const uint4*)(q + base + (size_t)p * HD);
            #pragma unroll
            for (int c = 0; c < 4; ++c) {
                uint4 u = qp[c];
                qf[c * 8 + 0] = BF2F_LO(u.x); qf[c * 8 + 1] = BF2F_HI(u.x);
                qf[c * 8 + 2] = BF2F_LO(u.y); qf[c * 8 + 3] = BF2F_HI(u.y);
                qf[c * 8 + 4] = BF2F_LO(u.z); qf[c * 8 + 5] = BF2F_HI(u.z);
                qf[c * 8 + 6] = BF2F_LO(u.w); qf[c * 8 + 7] = BF2F_HI(u.w);
            }
        }

        float of[32] = {};
        float sum = 0.f;
        #pragma unroll
        for (int i = 0; i < 7; ++i) {
            #pragma unroll
            for (int j = 0; j < 7; ++j) {
                const int hp = t + i * WWID + j;
                // --- score from K
                uint4 c0 = kh[0][hp], c1 = kh[1][hp], c2 = kh[2][hp], c3 = kh[3][hp];
                float s = 0.f;
                s = fmaf(BF2F_LO(c0.x), qf[0], s);  s = fmaf(BF2F_HI(c0.x), qf[1], s);
                s = fmaf(BF2F_LO(c0.y), qf[2], s);  s = fmaf(BF2F_HI(c0.y), qf[3], s);
                s = fmaf(BF2F_LO(c0.z), qf[4], s);  s = fmaf(BF2F_HI(c0.z), qf[5], s);
                s = fmaf(BF2F_LO(c0.w), qf[6], s);  s = fmaf(BF2F_HI(c0.w), qf[7], s);
                s = fmaf(BF2F_LO(c1.x), qf[8], s);  s = fmaf(BF2F_HI(c1.x), qf[9], s);
                s = fmaf(BF2F_LO(c1.y), qf[10], s); s = fmaf(BF2F_HI(c1.y), qf[11], s);
                s = fmaf(BF2F_LO(c1.z), qf[12], s); s = fmaf(BF2F_HI(c1.z), qf[13], s);
                s = fmaf(BF2F_LO(c1.w), qf[14], s); s = fmaf(BF2F_HI(c1.w), qf[15], s);
                s = fmaf(BF2F_LO(c2.x), qf[16], s); s = fmaf(BF2F_HI(c2.x), qf[17], s);
                s = fmaf(BF2F_LO(c2.y), qf[18], s); s = fmaf(BF2F_HI(c2.y), qf[19], s);
                s = fmaf(BF2F_LO(c2.z), qf[20], s); s = fmaf(BF2F_HI(c2.z), qf[21], s);
                s = fmaf(BF2F_LO(c2.w), qf[22], s); s = fmaf(BF2F_HI(c2.w), qf[23], s);
                s = fmaf(BF2F_LO(c3.x), qf[24], s); s = fmaf(BF2F_HI(c3.x), qf[25], s);
                s = fmaf(BF2F_LO(c3.y), qf[26], s); s = fmaf(BF2F_HI(c3.y), qf[27], s);
                s = fmaf(BF2F_LO(c3.z), qf[28], s); s = fmaf(BF2F_HI(c3.z), qf[29], s);
                s = fmaf(BF2F_LO(c3.w), qf[30], s); s = fmaf(BF2F_HI(c3.w), qf[31], s);
                const bool xv = (unsigned)(lx + j - 3) < WWID;
                const float e = __expf(s * SCALE);
                sum += xv ? e : 1.0f;
                const float wt = xv ? e : 0.0f;
                // --- accumulate V immediately (no weights array)
                uint4 d0 = vh[0][hp], d1 = vh[1][hp], d2 = vh[2][hp], d3 = vh[3][hp];
                of[0]  = fmaf(BF2F_LO(d0.x), wt, of[0]);  of[1]  = fmaf(BF2F_HI(d0.x), wt, of[1]);
                of[2]  = fmaf(BF2F_LO(d0.y), wt, of[2]);  of[3]  = fmaf(BF2F_HI(d0.y), wt, of[3]);
                of[4]  = fmaf(BF2F_LO(d0.z), wt, of[4]);  of[5]  = fmaf(BF2F_HI(d0.z), wt, of[5]);
                of[6]  = fmaf(BF2F_LO(d0.w), wt, of[6]);  of[7]  = fmaf(BF2F_HI(d0.w), wt, of[7]);
                of[8]  = fmaf(BF2F_LO(d1.x), wt, of[8]);  of[9]  = fmaf(BF2F_HI(d1.x), wt, of[9]);
                of[10] = fmaf(BF2F_LO(d1.y), wt, of[10]); of[11] = fmaf(BF2F_HI(d1.y), wt, of[11]);
                of[12] = fmaf(BF2F_LO(d1.z), wt, of[12]); of[13] = fmaf(BF2F_HI(d1.z), wt, of[13]);
                of[14] = fmaf(BF2F_LO(d1.w), wt, of[14]); of[15] = fmaf(BF2F_HI(d1.w), wt, of[15]);
                of[16] = fmaf(BF2F_LO(d2.x), wt, of[16]); of[17] = fmaf(BF2F_HI(d2.x), wt, of[17]);
                of[18] = fmaf(BF2F_LO(d2.y), wt, of[18]); of[19] = fmaf(BF2F_HI(d2.y), wt, of[19]);
                of[20] = fmaf(BF2F_LO(d2.z), wt, of[20]); of[21] = fmaf(BF2F_HI(d2.z), wt, of[21]);
                of[22] = fmaf(BF2F_LO(d2.w), wt, of[22]); of[23] = fmaf(BF2F_HI(d2.w), wt, of[23]);
                of[24] = fmaf(BF2F_LO(d3.x), wt, of[24]); of[25] = fmaf(BF2F_HI(d3.x), wt, of[25]);
                of[26] = fmaf(BF2F_LO(d3.y), wt, of[26]); of[27] = fmaf(BF2F_HI(d3.y), wt, of[27]);
                of[28] = fmaf(BF2F_LO(d3.z), wt, of[28]); of[29] = fmaf(BF2F_HI(d3.z), wt, of[29]);
                of[30] = fmaf(BF2F_LO(d3.w), wt, of[30]); of[31] = fmaf(BF2F_HI(d3.w), wt, of[31]);
            }
        }

        const float inv = 1.0f / sum;
        __hip_bfloat16* op = out + ((size_t)b * HW + p) * DM + h * HD;
        #pragma unroll
        for (int c = 0; c < 4; ++c) {
            union { uint4 u; __hip_bfloat16 s[8]; } pk;
            #pragma unroll
            for (int j = 0; j < 8; ++j)
                pk.s[j] = __float2bfloat16(of[c * 8 + j] * inv);
            *(uint4*)&op[c * 8] = pk.u;
        }
    }
}

// ---------------------------------------------------------------------------
extern "C" void kernel_launch(void* const* d_in, const int* in_sizes, int n_in,
                              void* d_out, int out_size, void* d_ws, size_t ws_size,
                              hipStream_t stream) {
    const float* x  = (const float*)d_in[0];
    const float* wq = (const float*)d_in[1];
    const float* bq = (const float*)d_in[2];
    const float* wk = (const float*)d_in[3];
    const float* bk = (const float*)d_in[4];
    const float* wv = (const float*)d_in[5];
    const float* bv = (const float*)d_in[6];
    const float* wo = (const float*)d_in[7];
    const float* bo = (const float*)d_in[8];
    float* out = (float*)d_out;

    const size_t NPC = (size_t)NB * HW * DM;
    __hip_bfloat16* xT   = (__hip_bfloat16*)d_ws;          // [b][p][c]
    __hip_bfloat16* wcat = xT + NPC;                       // [768][256]
    __hip_bfloat16* wob  = wcat + 768 * 256;               // [256][256]
    __hip_bfloat16* qb   = wob + 256 * 256;                // [b][h][p][d]
    __hip_bfloat16* kb   = qb + NPC;
    __hip_bfloat16* vb   = kb + NPC;
    __hip_bfloat16* attnT = vb + NPC;                      // [b][p][c]

    convert_w<<<256, 256, 0, stream>>>(wq, wk, wv, wo, wcat, wob);
    transpose_x<<<dim3(HW / 32, DM / 32, NB), 256, 0, stream>>>(x, xT);
    gemm_mfma<0><<<dim3(HW / 64, 6, NB), 256, 0, stream>>>(
        wcat, xT, bq, bk, bv, qb, kb, vb);
    attn_win<<<dim3(28, NHEAD, NB), 128, 0, stream>>>(qb, kb, vb, attnT);
    gemm_mfma<1><<<dim3(HW / 64, 2, NB), 256, 0, stream>>>(
        wob, attnT, bo, bo, bo, out, out, out);
}

// Round 5
// 116.873 us; speedup vs baseline: 3.0561x; 3.0561x over previous
//
#include <hip/hip_runtime.h>
#include <hip/hip_bf16.h>
#include <cstdint>

#define NHEAD 8
#define HD 32
#define DM 256
#define HH 56
#define WWID 56
#define HW 3136          // 56*56
#define NB 2
#define SCALE 0.17677669529663687f   // 32^-0.5

typedef unsigned int u32;
typedef __attribute__((ext_vector_type(8))) short short8;   // 8 bf16 = 4 VGPRs
typedef __attribute__((ext_vector_type(4))) float floatx4;

#define BF2F_LO(u) __uint_as_float((u) << 16)
#define BF2F_HI(u) __uint_as_float((u) & 0xffff0000u)

// ---------------------------------------------------------------------------
// Convert all four weight matrices fp32 -> bf16. wq,wk,wv stacked into
// wcat[768][256]; wo into wob[256][256].
// ---------------------------------------------------------------------------
__global__ __launch_bounds__(256) void convert_w(
    const float* __restrict__ wq, const float* __restrict__ wk,
    const float* __restrict__ wv, const float* __restrict__ wo,
    __hip_bfloat16* __restrict__ wcat, __hip_bfloat16* __restrict__ wob)
{
    const int gid = blockIdx.x * 256 + threadIdx.x;
    const int idx4 = gid << 2;                 // 0 .. 262140
    const int sel = idx4 >> 16;                // 0..3
    const int off = idx4 & 65535;
    const float* src = sel == 0 ? wq : (sel == 1 ? wk : (sel == 2 ? wv : wo));
    __hip_bfloat16* dst = sel < 3 ? (wcat + (sel << 16) + off) : (wob + off);
    float4 f = *(const float4*)&src[off];
    union { ushort4 u; __hip_bfloat16 s[4]; } pk;
    pk.s[0] = __float2bfloat16(f.x); pk.s[1] = __float2bfloat16(f.y);
    pk.s[2] = __float2bfloat16(f.z); pk.s[3] = __float2bfloat16(f.w);
    *(ushort4*)dst = pk.u;
}

// ---------------------------------------------------------------------------
// Transpose-convert x [b][c][p] fp32 -> xT [b][p][c] bf16 (c contiguous).
// ---------------------------------------------------------------------------
__global__ __launch_bounds__(256) void transpose_x(
    const float* __restrict__ x, __hip_bfloat16* __restrict__ xT)
{
    __shared__ float tile[32][33];
    const int b = blockIdx.z, p0 = blockIdx.x * 32, c0 = blockIdx.y * 32;
    const int tx = threadIdx.x & 31, ty = threadIdx.x >> 5;   // ty in [0,8)
    const float* xb = x + (size_t)b * DM * HW;
    #pragma unroll
    for (int i = 0; i < 4; ++i)
        tile[ty + i * 8][tx] = xb[(size_t)(c0 + ty + i * 8) * HW + p0 + tx];
    __syncthreads();
    __hip_bfloat16* xo = xT + (size_t)b * HW * DM;
    #pragma unroll
    for (int i = 0; i < 4; ++i)
        xo[(size_t)(p0 + ty + i * 8) * DM + c0 + tx] =
            __float2bfloat16(tile[tx][ty + i * 8]);
}

// ---------------------------------------------------------------------------
// MFMA GEMM: A bf16 [M][256] k-contig; B as Bm[b][n][k] k-contig.
// BM=128, BN=64, BK=32, 4 waves, wave = 64x32 via 4x2 tiles of 16x16x32.
// MODE 0: M=768 fused qkv -> q/k/v bf16 [b][h][p][d].
// MODE 1: M=256 out-proj  -> fp32 d_out [b][c][p].
// ---------------------------------------------------------------------------
template<int MODE>
__global__ __launch_bounds__(256) void gemm_mfma(
    const __hip_bfloat16* __restrict__ A,
    const __hip_bfloat16* __restrict__ Bm,
    const float* __restrict__ b0, const float* __restrict__ b1,
    const float* __restrict__ b2,
    void* __restrict__ o0, void* __restrict__ o1, void* __restrict__ o2)
{
    const int bb = blockIdx.z;
    const int n0 = blockIdx.x * 64;
    const int m0 = blockIdx.y * 128;
    const __hip_bfloat16* Bb = Bm + (size_t)bb * HW * DM + (size_t)n0 * DM;

    __shared__ __align__(16) __hip_bfloat16 As[128][40];
    __shared__ __align__(16) __hip_bfloat16 Bs[64][40];

    const int t = threadIdx.x;
    const int wave = t >> 6, lane = t & 63;
    const int quad = lane >> 4, l16 = lane & 15;
    const int mw = (wave & 1) * 64, nw = (wave >> 1) * 32;

    floatx4 acc[4][2] = {};

    const int am = t >> 2, ak = (t & 3) << 3;
    const int bn = t >> 2, bk = (t & 3) << 3;

    for (int k0g = 0; k0g < DM; k0g += 32) {
        *(uint4*)&As[am][ak]      = *(const uint4*)&A[(size_t)(m0 + am) * DM + k0g + ak];
        *(uint4*)&As[am + 64][ak] = *(const uint4*)&A[(size_t)(m0 + am + 64) * DM + k0g + ak];
        *(uint4*)&Bs[bn][bk]      = *(const uint4*)&Bb[(size_t)bn * DM + k0g + bk];
        __syncthreads();
        short8 af[4], bf[2];
        #pragma unroll
        for (int mt = 0; mt < 4; ++mt)
            af[mt] = *(const short8*)&As[mw + mt * 16 + l16][quad * 8];
        #pragma unroll
        for (int nt = 0; nt < 2; ++nt)
            bf[nt] = *(const short8*)&Bs[nw + nt * 16 + l16][quad * 8];
        #pragma unroll
        for (int mt = 0; mt < 4; ++mt)
            #pragma unroll
            for (int nt = 0; nt < 2; ++nt)
                acc[mt][nt] = __builtin_amdgcn_mfma_f32_16x16x32_bf16(
                    af[mt], bf[nt], acc[mt][nt], 0, 0, 0);
        __syncthreads();
    }

    if (MODE == 0) {
        #pragma unroll
        for (int mt = 0; mt < 4; ++mt) {
            const int gm = m0 + mw + mt * 16 + quad * 4;
            const int proj = gm >> 8;
            const int c = gm & 255;
            const int h = c >> 5, d0 = c & 31;
            const float* bptr = proj == 0 ? b0 : (proj == 1 ? b1 : b2);
            __hip_bfloat16* op = (__hip_bfloat16*)(proj == 0 ? o0 : (proj == 1 ? o1 : o2));
            const size_t base = ((size_t)(bb * NHEAD + h) * HW) * HD + d0;
            float bias[4] = {bptr[c], bptr[c + 1], bptr[c + 2], bptr[c + 3]};
            #pragma unroll
            for (int nt = 0; nt < 2; ++nt) {
                const int p = n0 + nw + nt * 16 + l16;
                union { ushort4 u; __hip_bfloat16 s[4]; } pk;
                #pragma unroll
                for (int r = 0; r < 4; ++r)
                    pk.s[r] = __float2bfloat16(acc[mt][nt][r] + bias[r]);
                *(ushort4*)&op[base + (size_t)p * HD] = pk.u;
            }
        }
    } else {
        float* yo = (float*)o0;
        #pragma unroll
        for (int mt = 0; mt < 4; ++mt) {
            const int gc = m0 + mw + mt * 16 + quad * 4;
            #pragma unroll
            for (int r = 0; r < 4; ++r) {
                const float bias = b0[gc + r];
                #pragma unroll
                for (int nt = 0; nt < 2; ++nt) {
                    const int p = n0 + nw + nt * 16 + l16;
                    yo[(size_t)(bb * DM + gc + r) * HW + p] = acc[mt][nt][r] + bias;
                }
            }
        }
    }
}

// ---------------------------------------------------------------------------
// Stage 2: sliding-window attention, d-split across lanes.
// Block = 448 threads = 112 positions (2 rows x 56) x 4 chunk-lanes.
// t = pos_local*4 + ch; each thread owns ONE 8-channel chunk: qf[8], of[8].
// Per-thread live state ~40 VGPR -> structurally no spills (R3/R4 lesson:
// any thread holding 64+ fp32 across the 49-iter loop spills at VGPR=256).
// LDS halo layout [pos'][chunk] (uint4): compute read addr = t*16 + const ->
// whole wave reads contiguous 1KB, stride-1, conflict-free.
// Score: partial 8-elem dot, full dot via shfl_xor(1)+shfl_xor(2) in the
// aligned 4-lane group. Zero-pad semantics: y-OOB rows + guards zeroed in
// LDS; x-invalid neighbors add exp(0)=1 to denom, 0 to numerator.
// ---------------------------------------------------------------------------
#define HROWS 8                    // 2 + 6 halo
#define HPOS  (HROWS * WWID)       // 448
#define HPP   (HPOS + 6)           // 454: +3 guard positions each side

__global__ __launch_bounds__(448) void attn_win(
    const __hip_bfloat16* __restrict__ q,
    const __hip_bfloat16* __restrict__ k,
    const __hip_bfloat16* __restrict__ v,
    __hip_bfloat16* __restrict__ out)
{
    __shared__ uint4 kh[HPP * 4];   // [pos'][chunk], 29,056 B
    __shared__ uint4 vh[HPP * 4];   // 29,056 B

    const int t = threadIdx.x;            // 0..447
    const int tile = blockIdx.x;          // 0..27
    const int h = blockIdx.y, b = blockIdx.z;
    const int y0 = tile * 2;
    const size_t base = (size_t)(b * NHEAD + h) * HW * HD;
    const __hip_bfloat16* kp = k + base;
    const __hip_bfloat16* vp = v + base;

    // ---- stage halo rows y0-3 .. y0+4 (zero y-OOB): 1792 uint4 each of K,V.
    // u = it*448 + t; pos = u>>2, ch = u&3 -> [pos][ch] flat = u; +12 = guard
    // offset (3 positions * 4 chunks). Consecutive t -> contiguous global.
    #pragma unroll
    for (int it = 0; it < 4; ++it) {
        const int u = t + it * 448;
        const int pos = u >> 2, ch = u & 3;
        const int hr = pos / WWID;
        const int gx = pos - hr * WWID;
        const int gy = y0 - 3 + hr;
        uint4 kv = make_uint4(0, 0, 0, 0), vv = make_uint4(0, 0, 0, 0);
        if ((unsigned)gy < HH) {
            const size_t g = (size_t)(gy * WWID + gx) * HD + (ch << 3);
            kv = *(const uint4*)&kp[g];
            vv = *(const uint4*)&vp[g];
        }
        kh[u + 12] = kv;
        vh[u + 12] = vv;
    }
    // zero guards: 3 low + 3 high positions, 4 chunks, both arrays (48 uint4)
    if (t < 48) {
        const int ps = t % 6;
        const int fi = (ps < 3 ? ps * 4 : (HPOS + ps) * 4) + ((t / 6) & 3);
        const uint4 z = make_uint4(0, 0, 0, 0);
        if (t < 24) kh[fi] = z; else vh[fi] = z;
    }
    __syncthreads();

    const int pl = t >> 2;                // local position 0..111
    const int ch = t & 3;                 // chunk 0..3
    const int lx = pl >= WWID ? pl - WWID : pl;   // x coordinate
    const int p = y0 * WWID + pl;         // global position

    // load my q chunk (8 channels) — one coalesced uint4 per thread
    float qf[8];
    {
        uint4 u = *(const uint4*)(q + base + (size_t)p * HD + (ch << 3));
        qf[0] = BF2F_LO(u.x); qf[1] = BF2F_HI(u.x);
        qf[2] = BF2F_LO(u.y); qf[3] = BF2F_HI(u.y);
        qf[4] = BF2F_LO(u.z); qf[5] = BF2F_HI(u.z);
        qf[6] = BF2F_LO(u.w); qf[7] = BF2F_HI(u.w);
    }

    const uint4* kb4 = kh + t;            // + (i*56+j)*4 per neighbor
    const uint4* vb4 = vh + t;

    float of[8] = {};
    float sum = 0.f;
    for (int i = 0; i < 7; ++i) {
        #pragma unroll
        for (int j = 0; j < 7; ++j) {
            const int off4 = (i * WWID + j) << 2;
            // partial score from my K chunk
            uint4 c0 = kb4[off4];
            float s;
            s = BF2F_LO(c0.x) * qf[0];
            s = fmaf(BF2F_HI(c0.x), qf[1], s);
            s = fmaf(BF2F_LO(c0.y), qf[2], s);
            s = fmaf(BF2F_HI(c0.y), qf[3], s);
            s = fmaf(BF2F_LO(c0.z), qf[4], s);
            s = fmaf(BF2F_HI(c0.z), qf[5], s);
            s = fmaf(BF2F_LO(c0.w), qf[6], s);
            s = fmaf(BF2F_HI(c0.w), qf[7], s);
            // reduce across the 4 chunk-lanes (aligned group)
            s += __shfl_xor(s, 1);
            s += __shfl_xor(s, 2);
            const bool xv = (unsigned)(lx + j - 3) < WWID;
            const float e = __expf(s * SCALE);
            sum += xv ? e : 1.0f;
            const float wt = xv ? e : 0.0f;
            // accumulate my V chunk
            uint4 d0 = vb4[off4];
            of[0] = fmaf(BF2F_LO(d0.x), wt, of[0]);
            of[1] = fmaf(BF2F_HI(d0.x), wt, of[1]);
            of[2] = fmaf(BF2F_LO(d0.y), wt, of[2]);
            of[3] = fmaf(BF2F_HI(d0.y), wt, of[3]);
            of[4] = fmaf(BF2F_LO(d0.z), wt, of[4]);
            of[5] = fmaf(BF2F_HI(d0.z), wt, of[5]);
            of[6] = fmaf(BF2F_LO(d0.w), wt, of[6]);
            of[7] = fmaf(BF2F_HI(d0.w), wt, of[7]);
        }
    }

    const float inv = 1.0f / sum;
    // write attnT[b][p][h*32 + ch*8 .. +7] — coalesced uint4 per thread
    __hip_bfloat16* op = out + ((size_t)b * HW + p) * DM + h * HD + (ch << 3);
    union { uint4 u; __hip_bfloat16 s[8]; } pk;
    #pragma unroll
    for (int j = 0; j < 8; ++j)
        pk.s[j] = __float2bfloat16(of[j] * inv);
    *(uint4*)op = pk.u;
}

// ---------------------------------------------------------------------------
extern "C" void kernel_launch(void* const* d_in, const int* in_sizes, int n_in,
                              void* d_out, int out_size, void* d_ws, size_t ws_size,
                              hipStream_t stream) {
    const float* x  = (const float*)d_in[0];
    const float* wq = (const float*)d_in[1];
    const float* bq = (const float*)d_in[2];
    const float* wk = (const float*)d_in[3];
    const float* bk = (const float*)d_in[4];
    const float* wv = (const float*)d_in[5];
    const float* bv = (const float*)d_in[6];
    const float* wo = (const float*)d_in[7];
    const float* bo = (const float*)d_in[8];
    float* out = (float*)d_out;

    const size_t NPC = (size_t)NB * HW * DM;
    __hip_bfloat16* xT   = (__hip_bfloat16*)d_ws;          // [b][p][c]
    __hip_bfloat16* wcat = xT + NPC;                       // [768][256]
    __hip_bfloat16* wob  = wcat + 768 * 256;               // [256][256]
    __hip_bfloat16* qb   = wob + 256 * 256;                // [b][h][p][d]
    __hip_bfloat16* kb   = qb + NPC;
    __hip_bfloat16* vb   = kb + NPC;
    __hip_bfloat16* attnT = vb + NPC;                      // [b][p][c]

    convert_w<<<256, 256, 0, stream>>>(wq, wk, wv, wo, wcat, wob);
    transpose_x<<<dim3(HW / 32, DM / 32, NB), 256, 0, stream>>>(x, xT);
    gemm_mfma<0><<<dim3(HW / 64, 6, NB), 256, 0, stream>>>(
        wcat, xT, bq, bk, bv, qb, kb, vb);
    attn_win<<<dim3(28, NHEAD, NB), 448, 0, stream>>>(qb, kb, vb, attnT);
    gemm_mfma<1><<<dim3(HW / 64, 2, NB), 256, 0, stream>>>(
        wob, attnT, bo, bo, bo, out, out, out);
}

// Round 6
// 111.660 us; speedup vs baseline: 3.1987x; 1.0467x over previous
//
#include <hip/hip_runtime.h>
#include <hip/hip_bf16.h>
#include <cstdint>

#define NHEAD 8
#define HD 32
#define DM 256
#define HH 56
#define WWID 56
#define HW 3136          // 56*56
#define NB 2
#define SCALE 0.17677669529663687f   // 32^-0.5

typedef _Float16 f16;
typedef __attribute__((ext_vector_type(2))) _Float16 f16x2;
typedef __attribute__((ext_vector_type(8))) _Float16 f16x8;   // 4 VGPRs
typedef __attribute__((ext_vector_type(4))) float floatx4;

union U16 { uint4 u; f16x2 h2[4]; f16 h[8]; };

// ---------------------------------------------------------------------------
// prep: fused weight-convert + x transpose (saves one launch vs R5).
// bid < 1568: transpose x [b][c][p] fp32 -> xT [b][p][c] f16 (32x32 tiles).
// bid >= 1568: convert wq/wk/wv -> wcat[768][256] f16, wo -> wob f16.
// Branch is block-uniform (no divergence across __syncthreads).
// ---------------------------------------------------------------------------
__global__ __launch_bounds__(256) void prep(
    const float* __restrict__ x,
    const float* __restrict__ wq, const float* __restrict__ wk,
    const float* __restrict__ wv, const float* __restrict__ wo,
    f16* __restrict__ xT, f16* __restrict__ wcat, f16* __restrict__ wob)
{
    const int bid = blockIdx.x;
    const int t = threadIdx.x;
    if (bid < 1568) {
        __shared__ float tile[32][33];
        const int b = bid / 784, r = bid - 784 * b;
        const int ct = r / 98;
        const int p0 = (r - ct * 98) * 32, c0 = ct * 32;
        const int tx = t & 31, ty = t >> 5;           // ty in [0,8)
        const float* xb = x + (size_t)b * DM * HW;
        #pragma unroll
        for (int i = 0; i < 4; ++i)
            tile[ty + i * 8][tx] = xb[(size_t)(c0 + ty + i * 8) * HW + p0 + tx];
        __syncthreads();
        f16* xo = xT + (size_t)b * HW * DM;
        #pragma unroll
        for (int i = 0; i < 4; ++i)
            xo[(size_t)(p0 + ty + i * 8) * DM + c0 + tx] =
                (f16)tile[tx][ty + i * 8];
    } else {
        const int gid = (bid - 1568) * 256 + t;
        const int idx4 = gid << 2;                // 0 .. 262140
        const int sel = idx4 >> 16;               // 0..3
        const int off = idx4 & 65535;
        const float* src = sel == 0 ? wq : (sel == 1 ? wk : (sel == 2 ? wv : wo));
        f16* dst = sel < 3 ? (wcat + (sel << 16) + off) : (wob + off);
        float4 f = *(const float4*)&src[off];
        union { ushort4 u; f16 h[4]; } pk;
        pk.h[0] = (f16)f.x; pk.h[1] = (f16)f.y;
        pk.h[2] = (f16)f.z; pk.h[3] = (f16)f.w;
        *(ushort4*)dst = pk.u;
    }
}

// ---------------------------------------------------------------------------
// MFMA GEMM: A f16 [M][256] k-contig; B as Bm[b][n][k] k-contig.
// BM=128, BN=64, BK=32, 4 waves, wave = 64x32 via 4x2 tiles of 16x16x32_f16.
// MODE 0: M=768 fused qkv -> q/k/v f16 [b][h][p][d]; q rows pre-scaled by
//         SCALE in the epilogue (so attn needs no per-score multiply).
// MODE 1: M=256 out-proj  -> fp32 d_out [b][c][p].
// ---------------------------------------------------------------------------
template<int MODE>
__global__ __launch_bounds__(256) void gemm_mfma(
    const f16* __restrict__ A,
    const f16* __restrict__ Bm,
    const float* __restrict__ b0, const float* __restrict__ b1,
    const float* __restrict__ b2,
    void* __restrict__ o0, void* __restrict__ o1, void* __restrict__ o2)
{
    const int bb = blockIdx.z;
    const int n0 = blockIdx.x * 64;
    const int m0 = blockIdx.y * 128;
    const f16* Bb = Bm + (size_t)bb * HW * DM + (size_t)n0 * DM;

    __shared__ __align__(16) f16 As[128][40];
    __shared__ __align__(16) f16 Bs[64][40];

    const int t = threadIdx.x;
    const int wave = t >> 6, lane = t & 63;
    const int quad = lane >> 4, l16 = lane & 15;
    const int mw = (wave & 1) * 64, nw = (wave >> 1) * 32;

    floatx4 acc[4][2] = {};

    const int am = t >> 2, ak = (t & 3) << 3;
    const int bn = t >> 2, bk = (t & 3) << 3;

    for (int k0g = 0; k0g < DM; k0g += 32) {
        *(uint4*)&As[am][ak]      = *(const uint4*)&A[(size_t)(m0 + am) * DM + k0g + ak];
        *(uint4*)&As[am + 64][ak] = *(const uint4*)&A[(size_t)(m0 + am + 64) * DM + k0g + ak];
        *(uint4*)&Bs[bn][bk]      = *(const uint4*)&Bb[(size_t)bn * DM + k0g + bk];
        __syncthreads();
        f16x8 af[4], bf[2];
        #pragma unroll
        for (int mt = 0; mt < 4; ++mt)
            af[mt] = *(const f16x8*)&As[mw + mt * 16 + l16][quad * 8];
        #pragma unroll
        for (int nt = 0; nt < 2; ++nt)
            bf[nt] = *(const f16x8*)&Bs[nw + nt * 16 + l16][quad * 8];
        #pragma unroll
        for (int mt = 0; mt < 4; ++mt)
            #pragma unroll
            for (int nt = 0; nt < 2; ++nt)
                acc[mt][nt] = __builtin_amdgcn_mfma_f32_16x16x32_f16(
                    af[mt], bf[nt], acc[mt][nt], 0, 0, 0);
        __syncthreads();
    }

    if (MODE == 0) {
        #pragma unroll
        for (int mt = 0; mt < 4; ++mt) {
            const int gm = m0 + mw + mt * 16 + quad * 4;
            const int proj = gm >> 8;
            const int c = gm & 255;
            const int h = c >> 5, d0 = c & 31;
            const float* bptr = proj == 0 ? b0 : (proj == 1 ? b1 : b2);
            f16* op = (f16*)(proj == 0 ? o0 : (proj == 1 ? o1 : o2));
            const float sc = proj == 0 ? SCALE : 1.0f;
            const size_t base = ((size_t)(bb * NHEAD + h) * HW) * HD + d0;
            float bias[4] = {bptr[c], bptr[c + 1], bptr[c + 2], bptr[c + 3]};
            #pragma unroll
            for (int nt = 0; nt < 2; ++nt) {
                const int p = n0 + nw + nt * 16 + l16;
                union { ushort4 u; f16 h[4]; } pk;
                #pragma unroll
                for (int r = 0; r < 4; ++r)
                    pk.h[r] = (f16)((acc[mt][nt][r] + bias[r]) * sc);
                *(ushort4*)&op[base + (size_t)p * HD] = pk.u;
            }
        }
    } else {
        float* yo = (float*)o0;
        #pragma unroll
        for (int mt = 0; mt < 4; ++mt) {
            const int gc = m0 + mw + mt * 16 + quad * 4;
            #pragma unroll
            for (int r = 0; r < 4; ++r) {
                const float bias = b0[gc + r];
                #pragma unroll
                for (int nt = 0; nt < 2; ++nt) {
                    const int p = n0 + nw + nt * 16 + l16;
                    yo[(size_t)(bb * DM + gc + r) * HW + p] = acc[mt][nt][r] + bias;
                }
            }
        }
    }
}

// ---------------------------------------------------------------------------
// Stage 2: sliding-window attention, d-split across lanes (R5 structure —
// ~40 VGPR live, no spills) + f16 arithmetic:
//  - K score: 4x v_dot2_f32_f16 (was 8 shift + 8 fma)
//  - V accum: float(h)*w+acc -> v_fma_mix_f32 (no separate cvt)
//  - q pre-scaled by SCALE in the qkv epilogue -> e = exp(s) directly.
// Block = 448 thr = 112 positions (2 rows x 56) x 4 chunk-lanes.
// LDS halo [pos'][chunk] uint4: compute read addr = t*16 + const ->
// wave reads contiguous 1KB, conflict-free. Zero-pad semantics: y-OOB rows
// + guards zeroed; x-invalid adds exp(0)=1 to denom, 0 to numerator.
// ---------------------------------------------------------------------------
#define HROWS 8                    // 2 + 6 halo
#define HPOS  (HROWS * WWID)       // 448
#define HPP   (HPOS + 6)           // 454: +3 guard positions each side

__global__ __launch_bounds__(448) void attn_win(
    const f16* __restrict__ q,
    const f16* __restrict__ k,
    const f16* __restrict__ v,
    f16* __restrict__ out)
{
    __shared__ uint4 kh[HPP * 4];   // 29,056 B
    __shared__ uint4 vh[HPP * 4];   // 29,056 B

    const int t = threadIdx.x;            // 0..447
    const int tile = blockIdx.x;          // 0..27
    const int h = blockIdx.y, b = blockIdx.z;
    const int y0 = tile * 2;
    const size_t base = (size_t)(b * NHEAD + h) * HW * HD;
    const f16* kp = k + base;
    const f16* vp = v + base;

    // ---- stage halo rows y0-3 .. y0+4 (zero y-OOB): 1792 uint4 each.
    #pragma unroll
    for (int it = 0; it < 4; ++it) {
        const int u = t + it * 448;
        const int pos = u >> 2, ch = u & 3;
        const int hr = pos / WWID;
        const int gx = pos - hr * WWID;
        const int gy = y0 - 3 + hr;
        uint4 kv = make_uint4(0, 0, 0, 0), vv = make_uint4(0, 0, 0, 0);
        if ((unsigned)gy < HH) {
            const size_t g = (size_t)(gy * WWID + gx) * HD + (ch << 3);
            kv = *(const uint4*)&kp[g];
            vv = *(const uint4*)&vp[g];
        }
        kh[u + 12] = kv;
        vh[u + 12] = vv;
    }
    if (t < 48) {   // zero guards: 3 low + 3 high positions x 4 chunks, both
        const int ps = t % 6;
        const int fi = (ps < 3 ? ps * 4 : (HPOS + ps) * 4) + ((t / 6) & 3);
        const uint4 z = make_uint4(0, 0, 0, 0);
        if (t < 24) kh[fi] = z; else vh[fi] = z;
    }
    __syncthreads();

    const int pl = t >> 2;                // local position 0..111
    const int ch = t & 3;                 // chunk 0..3
    const int lx = pl >= WWID ? pl - WWID : pl;
    const int p = y0 * WWID + pl;

    // my q chunk (8 channels, already SCALE-scaled) — one coalesced uint4
    U16 qu;
    qu.u = *(const uint4*)(q + base + (size_t)p * HD + (ch << 3));

    const uint4* kb4 = kh + t;            // + (i*56+j)*4 per neighbor
    const uint4* vb4 = vh + t;

    float of[8] = {};
    float sum = 0.f;
    for (int i = 0; i < 7; ++i) {
        #pragma unroll
        for (int j = 0; j < 7; ++j) {
            const int off4 = (i * WWID + j) << 2;
            U16 ku; ku.u = kb4[off4];
            float s;
            s = __builtin_amdgcn_fdot2(ku.h2[0], qu.h2[0], 0.0f, false);
            s = __builtin_amdgcn_fdot2(ku.h2[1], qu.h2[1], s, false);
            s = __builtin_amdgcn_fdot2(ku.h2[2], qu.h2[2], s, false);
            s = __builtin_amdgcn_fdot2(ku.h2[3], qu.h2[3], s, false);
            s += __shfl_xor(s, 1);
            s += __shfl_xor(s, 2);
            const bool xv = (unsigned)(lx + j - 3) < WWID;
            const float e = __expf(s);
            sum += xv ? e : 1.0f;
            const float wt = xv ? e : 0.0f;
            U16 vu; vu.u = vb4[off4];
            of[0] = fmaf((float)vu.h[0], wt, of[0]);
            of[1] = fmaf((float)vu.h[1], wt, of[1]);
            of[2] = fmaf((float)vu.h[2], wt, of[2]);
            of[3] = fmaf((float)vu.h[3], wt, of[3]);
            of[4] = fmaf((float)vu.h[4], wt, of[4]);
            of[5] = fmaf((float)vu.h[5], wt, of[5]);
            of[6] = fmaf((float)vu.h[6], wt, of[6]);
            of[7] = fmaf((float)vu.h[7], wt, of[7]);
        }
    }

    const float inv = 1.0f / sum;
    f16* op = out + ((size_t)b * HW + p) * DM + h * HD + (ch << 3);
    U16 ou;
    #pragma unroll
    for (int j = 0; j < 8; ++j)
        ou.h[j] = (f16)(of[j] * inv);
    *(uint4*)op = ou.u;
}

// ---------------------------------------------------------------------------
extern "C" void kernel_launch(void* const* d_in, const int* in_sizes, int n_in,
                              void* d_out, int out_size, void* d_ws, size_t ws_size,
                              hipStream_t stream) {
    const float* x  = (const float*)d_in[0];
    const float* wq = (const float*)d_in[1];
    const float* bq = (const float*)d_in[2];
    const float* wk = (const float*)d_in[3];
    const float* bk = (const float*)d_in[4];
    const float* wv = (const float*)d_in[5];
    const float* bv = (const float*)d_in[6];
    const float* wo = (const float*)d_in[7];
    const float* bo = (const float*)d_in[8];
    float* out = (float*)d_out;

    const size_t NPC = (size_t)NB * HW * DM;
    f16* xT    = (f16*)d_ws;               // [b][p][c]
    f16* wcat  = xT + NPC;                 // [768][256]
    f16* wob   = wcat + 768 * 256;         // [256][256]
    f16* qb    = wob + 256 * 256;          // [b][h][p][d], pre-scaled
    f16* kb    = qb + NPC;
    f16* vb    = kb + NPC;
    f16* attnT = vb + NPC;                 // [b][p][c]

    prep<<<1824, 256, 0, stream>>>(x, wq, wk, wv, wo, xT, wcat, wob);
    gemm_mfma<0><<<dim3(HW / 64, 6, NB), 256, 0, stream>>>(
        wcat, xT, bq, bk, bv, qb, kb, vb);
    attn_win<<<dim3(28, NHEAD, NB), 448, 0, stream>>>(qb, kb, vb, attnT);
    gemm_mfma<1><<<dim3(HW / 64, 2, NB), 256, 0, stream>>>(
        wob, attnT, bo, bo, bo, out, out, out);
}